// Round 2
// baseline (1362.976 us; speedup 1.0000x reference)
//
#include <hip/hip_runtime.h>

// LocalDynamicGraph edge features:
//   out[b,n,c2,k] = x[b, idx[b,n,k], c2] - x[b,n,c2]   for c2 <  C
//   out[b,n,c2,k] = x[b, n, c2-C]                      for c2 >= C
// Shapes: x (B=8, N=16384, C=64) fp32, idx (B,N,K=20) int, out (B,N,2C,K) fp32.
// Pure memory-bound: 1.342 GB output writes dominate. Strategy: block = 2 points,
// stage transposed neighbor tile in LDS so output writes are linear float4.

#define BC   64     // channels C
#define KK   20     // neighbors K
#define NSHF 14     // log2(N) = log2(16384)
#define PPB  2      // points per block
#define BLK  256

__global__ __launch_bounds__(BLK)
void ldg_edge_kernel(const float* __restrict__ x,
                     const int*   __restrict__ idx,
                     float*       __restrict__ out) {
    __shared__ float nbrT[PPB][BC][KK];  // transposed: [point][channel][k]
    __shared__ float cen [PPB][BC];
    __shared__ int   sidx[PPB][KK];

    const int t  = threadIdx.x;
    const int p0 = blockIdx.x * PPB;     // global point index (b*N+n) of point 0

    // --- stage neighbor indices (PPB*K = 40 ints) and center rows (PPB*C = 128 f32)
    if (t < PPB * KK) {
        int pp = t / KK, kk = t - pp * KK;
        sidx[pp][kk] = idx[(p0 + pp) * KK + kk];
    }
    if (t < PPB * BC) {
        int pp = t >> 6, col = t & 63;
        cen[pp][col] = x[(p0 + pp) * BC + col];
    }
    __syncthreads();

    // --- gather K neighbor rows per point into transposed LDS tile.
    // j enumerates PPB*K*C = 2560 elements; 64 consecutive lanes read 64
    // consecutive channels of one neighbor row -> coalesced 256B global reads.
    #pragma unroll
    for (int i = 0; i < (PPB * KK * BC) / BLK; ++i) {
        int j   = t + i * BLK;
        int pp  = j / (KK * BC);
        int rem = j - pp * (KK * BC);
        int r   = rem >> 6;              // neighbor slot k
        int col = rem & 63;              // channel
        int P   = p0 + pp;
        int b   = P >> NSHF;             // batch
        int row = sidx[pp][r];           // neighbor index within batch
        nbrT[pp][col][r] = x[(((b << NSHF) + row) << 6) + col];
    }
    __syncthreads();

    // --- write output: per point 2*C*K = 2560 f32 = 640 float4 (K=20 -> 5 f4/row,
    // each float4 within one c2 row). Thread-linear q -> perfectly coalesced
    // global stores and linear (conflict-free) ds_read_b128 from nbrT.
    float4* out4 = (float4*)(out + (long long)p0 * (2 * BC * KK));
    #pragma unroll
    for (int i = 0; i < (PPB * 2 * BC * KK / 4) / BLK; ++i) {
        int q  = t + i * BLK;
        int pp = q / (2 * BC * KK / 4);              // / 640
        int e4 = q - pp * (2 * BC * KK / 4);
        int c2 = e4 / (KK / 4);                      // / 5
        int k0 = (e4 - c2 * (KK / 4)) << 2;
        float4 v;
        if (c2 < BC) {
            float  cv = cen[pp][c2];
            float4 nv = *(const float4*)&nbrT[pp][c2][k0];
            v = make_float4(nv.x - cv, nv.y - cv, nv.z - cv, nv.w - cv);
        } else {
            float cv = cen[pp][c2 - BC];
            v = make_float4(cv, cv, cv, cv);
        }
        out4[q] = v;
    }
}

extern "C" void kernel_launch(void* const* d_in, const int* in_sizes, int n_in,
                              void* d_out, int out_size, void* d_ws, size_t ws_size,
                              hipStream_t stream) {
    const float* x   = (const float*)d_in[0];
    const int*   idx = (const int*)d_in[1];
    float*       out = (float*)d_out;

    const int total_points = in_sizes[0] / BC;       // B*N = 131072
    const int blocks = total_points / PPB;           // 65536

    ldg_edge_kernel<<<blocks, BLK, 0, stream>>>(x, idx, out);
}